// Round 1
// baseline (316.384 us; speedup 1.0000x reference)
//
#include <hip/hip_runtime.h>
#include <math.h>

// LinearAutoregressiveHMM fused kernel for MI355X (gfx950).
// B=8192, L=64, C=4, K=8, P=16. One kernel does: AR scores (causal conv),
// emission log-probs, HMM forward recursion, argmax state, P-step rollout.
// Block = 256 threads (4 waves); each wave owns 2 batch rows; 8 rows/block.

namespace {
constexpr int BB   = 8192;
constexpr int LL   = 64;
constexpr int CCH  = 4;
constexpr int KK   = 8;
constexpr int PP   = 16;
constexpr int BPB  = 8;    // batch rows per block
constexpr int NTHR = 256;
}

__global__ __launch_bounds__(256, 3)
void lahmm_fused(const float* __restrict__ em,  const float* __restrict__ trm,
                 const float* __restrict__ ini, const float* __restrict__ mns,
                 const float* __restrict__ cvc, const float* __restrict__ Wg,
                 float* __restrict__ out)
{
    // LDS budget ~53 KB -> 3 blocks/CU (12 waves/CU)
    __shared__ __align__(16) float sW[KK * CCH * LL * CCH];   // 8192 f: [k][c][j*4+c']
    __shared__ __align__(16) float sBuf[BPB][576];            // per b: 144 timesteps x 4 ch
    __shared__ __align__(16) float sElp[BPB][8][KK];          // elp staging, chunks of 8 t
    __shared__ float sLT[KK][KK];      // log(softmax(trans)+1e-8), [j][k]
    __shared__ float sLI[KK];          // log(softmax(init))
    __shared__ float sMean[KK][CCH];
    __shared__ float sVar[KK][CCH];
    __shared__ float sLogdet[KK];
    __shared__ int   sNs[KK];          // argmax of each trans row
    __shared__ unsigned char sChain[KK][PP];  // state chain from each start state

    const int tid   = threadIdx.x;
    const int lane  = tid & 63;
    const int wv    = tid >> 6;
    const int bBase = blockIdx.x * BPB;

    // ---------------- Phase 0: stage W, emissions, small tables ----------------
    const float4* Wg4 = reinterpret_cast<const float4*>(Wg);
    float4* sW4 = reinterpret_cast<float4*>(sW);
#pragma unroll
    for (int r = 0; r < 8; ++r) sW4[tid + r * 256] = Wg4[tid + r * 256];

    const float4* em4 = reinterpret_cast<const float4*>(em);
    float4* sBuf4 = reinterpret_cast<float4*>(&sBuf[0][0]);
#pragma unroll
    for (int r = 0; r < 2; ++r) {
        int idx = tid + r * 256;            // 0..511 covers 8 b x 64 rows
        int bl = idx >> 6, row = idx & 63;
        sBuf4[bl * 144 + 64 + row] = em4[(bBase + bl) * 64 + row];
        sBuf4[bl * 144 + row]      = make_float4(0.f, 0.f, 0.f, 0.f);
    }

    if (tid < KK) {
        // transition row tid: softmax -> log(+1e-8); next-state argmax (raw row: monotone)
        float row[KK];
        float m = -INFINITY;
#pragma unroll
        for (int k = 0; k < KK; ++k) { row[k] = trm[tid * KK + k]; m = fmaxf(m, row[k]); }
        float se = 0.f;
#pragma unroll
        for (int k = 0; k < KK; ++k) se += expf(row[k] - m);
        int best = 0; float bv = row[0];
#pragma unroll
        for (int k = 1; k < KK; ++k) if (row[k] > bv) { bv = row[k]; best = k; }
        sNs[tid] = best;
#pragma unroll
        for (int k = 0; k < KK; ++k) sLT[tid][k] = logf(expf(row[k] - m) / se + 1e-8f);
    } else if (tid == 8) {
        float x[KK]; float m = -INFINITY;
#pragma unroll
        for (int k = 0; k < KK; ++k) { x[k] = ini[k]; m = fmaxf(m, x[k]); }
        float se = 0.f;
#pragma unroll
        for (int k = 0; k < KK; ++k) se += expf(x[k] - m);
#pragma unroll
        for (int k = 0; k < KK; ++k) sLI[k] = logf(expf(x[k] - m) / se);
    } else if (tid >= 32 && tid < 64) {
        int i = tid - 32;                   // 0..31 covers K*C
        (&sMean[0][0])[i] = mns[i];
        (&sVar[0][0])[i]  = expf(cvc[i]) + 1e-6f;
    }
    __syncthreads();
    if (tid < KK) {
        float ld = 0.f;
#pragma unroll
        for (int c = 0; c < CCH; ++c) ld += logf(sVar[tid][c]);
        sLogdet[tid] = ld;
        int s = tid;
#pragma unroll
        for (int p = 0; p < PP; ++p) { s = sNs[s]; sChain[tid][p] = (unsigned char)s; }
    }
    __syncthreads();

    // ---------------- Phase A: AR scores (the 8.6 GFLOP conv) ----------------
    const int b0l = wv * 2, b1l = wv * 2 + 1;
    const float4* bv0 = reinterpret_cast<const float4*>(&sBuf[b0l][0]);
    const float4* bv1 = reinterpret_cast<const float4*>(&sBuf[b1l][0]);
    const float4* Wv  = reinterpret_cast<const float4*>(sW);
    const int t = lane;   // lane owns output timestep t for both its b's

    float acc0[KK][CCH], acc1[KK][CCH];
#pragma unroll
    for (int k = 0; k < KK; ++k)
#pragma unroll
        for (int c = 0; c < CCH; ++c) { acc0[k][c] = 0.f; acc1[k][c] = 0.f; }

    for (int j = 0; j < LL; ++j) {
        float4 x0 = bv0[t + j];            // per-lane contiguous b128 (bandwidth-optimal)
        float4 x1 = bv1[t + j];
#pragma unroll
        for (int k = 0; k < KK; ++k) {
#pragma unroll
            for (int c = 0; c < CCH; ++c) {
                float4 w = Wv[(k * CCH + c) * LL + j];   // wave-uniform b128 -> broadcast
                float a0 = acc0[k][c], a1 = acc1[k][c];
                a0 = fmaf(x0.x, w.x, a0); a1 = fmaf(x1.x, w.x, a1);
                a0 = fmaf(x0.y, w.y, a0); a1 = fmaf(x1.y, w.y, a1);
                a0 = fmaf(x0.z, w.z, a0); a1 = fmaf(x1.z, w.z, a1);
                a0 = fmaf(x0.w, w.w, a0); a1 = fmaf(x1.w, w.w, a1);
                acc0[k][c] = a0; acc1[k][c] = a1;
            }
        }
    }

    // emission log-probs for (t, all k), both b's
    float e0[KK], e1[KK];
    {
        float4 tg0 = bv0[64 + t], tg1 = bv1[64 + t];
        const float c2pi = 7.3515082656373819f;   // C * log(2*pi)
#pragma unroll
        for (int k = 0; k < KK; ++k) {
            float mh0 = 0.f, mh1 = 0.f;
#pragma unroll
            for (int c = 0; c < CCH; ++c) {
                float mu = sMean[k][c], va = sVar[k][c];
                float g0 = (c == 0) ? tg0.x : (c == 1) ? tg0.y : (c == 2) ? tg0.z : tg0.w;
                float g1 = (c == 0) ? tg1.x : (c == 1) ? tg1.y : (c == 2) ? tg1.z : tg1.w;
                float d0 = g0 - (mu + acc0[k][c]);
                float d1 = g1 - (mu + acc1[k][c]);
                mh0 += d0 * d0 / va;
                mh1 += d1 * d1 / va;
            }
            e0[k] = -0.5f * (mh0 + sLogdet[k] + c2pi);
            e1[k] = -0.5f * (mh1 + sLogdet[k] + c2pi);
        }
    }

    // ---------------- Phase B: HMM forward recursion ----------------
    // lane = (k,j): k = lane>>3 output state, j = lane&7 source state
    const int kf = lane >> 3, jf = lane & 7;
    const float lt  = sLT[jf][kf];
    const float liJ = sLI[jf], liK = sLI[kf];
    float laP0 = 0.f, laP1 = 0.f;   // la_prev[jf]
    float laN0 = 0.f, laN1 = 0.f;   // la_new[kf]

    for (int ch = 0; ch < 8; ++ch) {
        if ((t >> 3) == ch) {       // stage this chunk's elp rows
            int tt = t & 7;
            float4* dst0 = reinterpret_cast<float4*>(&sElp[b0l][tt][0]);
            dst0[0] = make_float4(e0[0], e0[1], e0[2], e0[3]);
            dst0[1] = make_float4(e0[4], e0[5], e0[6], e0[7]);
            float4* dst1 = reinterpret_cast<float4*>(&sElp[b1l][tt][0]);
            dst1[0] = make_float4(e1[0], e1[1], e1[2], e1[3]);
            dst1[1] = make_float4(e1[4], e1[5], e1[6], e1[7]);
        }
        __syncthreads();
#pragma unroll
        for (int ts = 0; ts < 8; ++ts) {
            if (ch == 0 && ts == 0) {
                laP0 = liJ + sElp[b0l][0][jf];
                laP1 = liJ + sElp[b1l][0][jf];
                laN0 = liK + sElp[b0l][0][kf];
                laN1 = liK + sElp[b1l][0][kf];
            } else {
                float t0 = laP0 + lt, t1 = laP1 + lt;
                float m0 = t0, m1 = t1;
                m0 = fmaxf(m0, __shfl_xor(m0, 1)); m1 = fmaxf(m1, __shfl_xor(m1, 1));
                m0 = fmaxf(m0, __shfl_xor(m0, 2)); m1 = fmaxf(m1, __shfl_xor(m1, 2));
                m0 = fmaxf(m0, __shfl_xor(m0, 4)); m1 = fmaxf(m1, __shfl_xor(m1, 4));
                float s0 = expf(t0 - m0), s1 = expf(t1 - m1);
                s0 += __shfl_xor(s0, 1); s1 += __shfl_xor(s1, 1);
                s0 += __shfl_xor(s0, 2); s1 += __shfl_xor(s1, 2);
                s0 += __shfl_xor(s0, 4); s1 += __shfl_xor(s1, 4);
                laN0 = m0 + logf(s0) + sElp[b0l][ts][kf];
                laN1 = m1 + logf(s1) + sElp[b1l][ts][kf];
                laP0 = __shfl(laN0, jf << 3);   // redistribute la[j] for next step
                laP1 = __shfl(laN1, jf << 3);
            }
        }
        __syncthreads();
    }

    // argmax state (first-index on ties, like jnp.argmax)
    float bst0 = -INFINITY, bst1 = -INFINITY;
    int s00 = 0, s01 = 0;
#pragma unroll
    for (int k = 0; k < KK; ++k) {
        float v0 = __shfl(laN0, k * 8);
        float v1 = __shfl(laN1, k * 8);
        if (v0 > bst0) { bst0 = v0; s00 = k; }
        if (v1 > bst1) { bst1 = v1; s01 = k; }
    }

    // ---------------- Phase C: P-step autoregressive rollout ----------------
    float* bf0 = &sBuf[b0l][0];
    float* bf1 = &sBuf[b1l][0];
    for (int p = 0; p < PP; ++p) {
        int sa = (int)sChain[s00][p];
        int sb = (int)sChain[s01][p];
        float4 x0 = bv0[64 + p + t];       // window [p, p+63] of rolling buffer
        float4 x1 = bv1[64 + p + t];
        float pr0[CCH], pr1[CCH];
#pragma unroll
        for (int c = 0; c < CCH; ++c) {
            float4 w0 = Wv[(sa * CCH + c) * LL + t];
            float4 w1 = Wv[(sb * CCH + c) * LL + t];
            pr0[c] = fmaf(x0.w, w0.w, fmaf(x0.z, w0.z, fmaf(x0.y, w0.y, x0.x * w0.x)));
            pr1[c] = fmaf(x1.w, w1.w, fmaf(x1.z, w1.z, fmaf(x1.y, w1.y, x1.x * w1.x)));
        }
#pragma unroll
        for (int c = 0; c < CCH; ++c) {
#pragma unroll
            for (int d = 1; d < 64; d <<= 1) {
                pr0[c] += __shfl_xor(pr0[c], d);
                pr1[c] += __shfl_xor(pr1[c], d);
            }
            pr0[c] += sMean[sa][c];
            pr1[c] += sMean[sb][c];
        }
        int cw = lane & 3;
        float v0 = (cw == 0) ? pr0[0] : (cw == 1) ? pr0[1] : (cw == 2) ? pr0[2] : pr0[3];
        float v1 = (cw == 0) ? pr1[0] : (cw == 1) ? pr1[1] : (cw == 2) ? pr1[2] : pr1[3];
        if (lane < 4) {
            bf0[(128 + p) * 4 + cw] = v0;                       // append pred to buffer
            out[(bBase + b0l) * (PP * CCH) + p * CCH + cw] = v0;
        } else if (lane < 8) {
            bf1[(128 + p) * 4 + cw] = v1;
            out[(bBase + b1l) * (PP * CCH) + p * CCH + cw] = v1;
        }
        __syncthreads();
    }
}

extern "C" void kernel_launch(void* const* d_in, const int* in_sizes, int n_in,
                              void* d_out, int out_size, void* d_ws, size_t ws_size,
                              hipStream_t stream) {
    (void)in_sizes; (void)n_in; (void)d_ws; (void)ws_size; (void)out_size;
    const float* em  = (const float*)d_in[0];
    const float* trm = (const float*)d_in[1];
    const float* ini = (const float*)d_in[2];
    const float* mns = (const float*)d_in[3];
    const float* cvc = (const float*)d_in[4];
    const float* Wg  = (const float*)d_in[5];
    float* out = (float*)d_out;
    dim3 grid(BB / BPB), block(NTHR);
    hipLaunchKernelGGL(lahmm_fused, grid, block, 0, stream,
                       em, trm, ini, mns, cvc, Wg, out);
}

// Round 2
// 242.290 us; speedup vs baseline: 1.3058x; 1.3058x over previous
//
#include <hip/hip_runtime.h>
#include <math.h>

// LinearAutoregressiveHMM fused kernel for MI355X (gfx950).
// B=8192, L=64, C=4, K=8, P=16. One kernel: AR scores (causal conv),
// emission log-probs, HMM forward recursion, argmax state, P-step rollout.
// Block = 256 threads (4 waves); each wave owns 2 batch rows; 8 rows/block.
//
// R2 changes vs R1 (289us, VGPR=68 -> acc eviction, occ 21%):
//  - Phase A split into two k-halves: 32 live accs, fits registers.
//  - W read from GLOBAL with wave-uniform index (scalar/broadcast, L1-hot),
//    LDS W staging removed: LDS 54KB -> 20KB, launch_bounds(256,4).
//  - j loop starts at 1 (j=0 provably multiplies only zero-padding).
//  - Phases B/C numerics unchanged from the passing R1 version.

namespace {
constexpr int BB   = 8192;
constexpr int LL   = 64;
constexpr int CCH  = 4;
constexpr int KK   = 8;
constexpr int PP   = 16;
constexpr int BPB  = 8;    // batch rows per block
constexpr int NTHR = 256;
}

__global__ __launch_bounds__(256, 4)
void lahmm_fused(const float* __restrict__ em,  const float* __restrict__ trm,
                 const float* __restrict__ ini, const float* __restrict__ mns,
                 const float* __restrict__ cvc, const float* __restrict__ Wg,
                 float* __restrict__ out)
{
    __shared__ __align__(16) float sBuf[BPB][576];            // per b: 144 timesteps x 4 ch
    __shared__ __align__(16) float sElp[BPB][8][KK];          // elp staging, chunks of 8 t
    __shared__ float sLT[KK][KK];      // log(softmax(trans)+1e-8), [j][k]
    __shared__ float sLI[KK];          // log(softmax(init))
    __shared__ float sMean[KK][CCH];
    __shared__ float sVar[KK][CCH];
    __shared__ float sLogdet[KK];
    __shared__ int   sNs[KK];          // argmax of each trans row
    __shared__ unsigned char sChain[KK][PP];  // state chain from each start state

    const int tid   = threadIdx.x;
    const int lane  = tid & 63;
    const int wv    = tid >> 6;
    const int bBase = blockIdx.x * BPB;

    // ---------------- Phase 0: stage emissions + small tables ----------------
    const float4* em4 = reinterpret_cast<const float4*>(em);
    float4* sBuf4 = reinterpret_cast<float4*>(&sBuf[0][0]);
#pragma unroll
    for (int r = 0; r < 2; ++r) {
        int idx = tid + r * 256;            // 0..511 covers 8 b x 64 rows
        int bl = idx >> 6, row = idx & 63;
        sBuf4[bl * 144 + 64 + row] = em4[(bBase + bl) * 64 + row];
        sBuf4[bl * 144 + row]      = make_float4(0.f, 0.f, 0.f, 0.f);
    }

    if (tid < KK) {
        // transition row tid: softmax -> log(+1e-8); next-state argmax (raw row: monotone)
        float row[KK];
        float m = -INFINITY;
#pragma unroll
        for (int k = 0; k < KK; ++k) { row[k] = trm[tid * KK + k]; m = fmaxf(m, row[k]); }
        float se = 0.f;
#pragma unroll
        for (int k = 0; k < KK; ++k) se += expf(row[k] - m);
        int best = 0; float bv = row[0];
#pragma unroll
        for (int k = 1; k < KK; ++k) if (row[k] > bv) { bv = row[k]; best = k; }
        sNs[tid] = best;
#pragma unroll
        for (int k = 0; k < KK; ++k) sLT[tid][k] = logf(expf(row[k] - m) / se + 1e-8f);
    } else if (tid == 8) {
        float x[KK]; float m = -INFINITY;
#pragma unroll
        for (int k = 0; k < KK; ++k) { x[k] = ini[k]; m = fmaxf(m, x[k]); }
        float se = 0.f;
#pragma unroll
        for (int k = 0; k < KK; ++k) se += expf(x[k] - m);
#pragma unroll
        for (int k = 0; k < KK; ++k) sLI[k] = logf(expf(x[k] - m) / se);
    } else if (tid >= 32 && tid < 64) {
        int i = tid - 32;                   // 0..31 covers K*C
        (&sMean[0][0])[i] = mns[i];
        (&sVar[0][0])[i]  = expf(cvc[i]) + 1e-6f;
    }
    __syncthreads();
    if (tid < KK) {
        float ld = 0.f;
#pragma unroll
        for (int c = 0; c < CCH; ++c) ld += logf(sVar[tid][c]);
        sLogdet[tid] = ld;
        int s = tid;
#pragma unroll
        for (int p = 0; p < PP; ++p) { s = sNs[s]; sChain[tid][p] = (unsigned char)s; }
    }
    __syncthreads();

    // ---------------- Phase A: AR scores (the 8.6 GFLOP conv) ----------------
    // Two k-half passes keep live accumulators at 32 (fits VGPRs, pipelines).
    const int b0l = wv * 2, b1l = wv * 2 + 1;
    const float4* bv0 = reinterpret_cast<const float4*>(&sBuf[b0l][0]);
    const float4* bv1 = reinterpret_cast<const float4*>(&sBuf[b1l][0]);
    const float4* Wv  = reinterpret_cast<const float4*>(Wg);  // [k][c][j] float4 of c'
    const int t = lane;   // lane owns output timestep t for both its b's

    float e0[KK], e1[KK];
    const float c2pi = 7.3515082656373819f;   // C * log(2*pi)

#pragma unroll
    for (int kh = 0; kh < 2; ++kh) {
        float acc0[4][CCH], acc1[4][CCH];
#pragma unroll
        for (int q = 0; q < 4; ++q)
#pragma unroll
            for (int c = 0; c < CCH; ++c) { acc0[q][c] = 0.f; acc1[q][c] = 0.f; }

#pragma unroll 2
        for (int j = 1; j < LL; ++j) {      // j=0 hits only the zero pad
            float4 x0 = bv0[t + j];         // per-lane contiguous b128
            float4 x1 = bv1[t + j];
#pragma unroll
            for (int q = 0; q < 4; ++q) {
#pragma unroll
                for (int c = 0; c < CCH; ++c) {
                    // wave-uniform index -> scalar/broadcast load, L1-resident (32KB)
                    float4 w = Wv[((kh * 4 + q) * CCH + c) * LL + j];
                    float a0 = acc0[q][c], a1 = acc1[q][c];
                    a0 = fmaf(x0.x, w.x, a0); a1 = fmaf(x1.x, w.x, a1);
                    a0 = fmaf(x0.y, w.y, a0); a1 = fmaf(x1.y, w.y, a1);
                    a0 = fmaf(x0.z, w.z, a0); a1 = fmaf(x1.z, w.z, a1);
                    a0 = fmaf(x0.w, w.w, a0); a1 = fmaf(x1.w, w.w, a1);
                    acc0[q][c] = a0; acc1[q][c] = a1;
                }
            }
        }

        // emission log-probs for this k-half (numerics identical to R1)
        float4 tg0 = bv0[64 + t], tg1 = bv1[64 + t];
#pragma unroll
        for (int q = 0; q < 4; ++q) {
            int k = kh * 4 + q;
            float mh0 = 0.f, mh1 = 0.f;
#pragma unroll
            for (int c = 0; c < CCH; ++c) {
                float mu = sMean[k][c], va = sVar[k][c];
                float g0 = (c == 0) ? tg0.x : (c == 1) ? tg0.y : (c == 2) ? tg0.z : tg0.w;
                float g1 = (c == 0) ? tg1.x : (c == 1) ? tg1.y : (c == 2) ? tg1.z : tg1.w;
                float d0 = g0 - (mu + acc0[q][c]);
                float d1 = g1 - (mu + acc1[q][c]);
                mh0 += d0 * d0 / va;
                mh1 += d1 * d1 / va;
            }
            e0[k] = -0.5f * (mh0 + sLogdet[k] + c2pi);
            e1[k] = -0.5f * (mh1 + sLogdet[k] + c2pi);
        }
    }

    // ---------------- Phase B: HMM forward recursion ----------------
    // lane = (k,j): k = lane>>3 output state, j = lane&7 source state
    const int kf = lane >> 3, jf = lane & 7;
    const float lt  = sLT[jf][kf];
    const float liJ = sLI[jf], liK = sLI[kf];
    float laP0 = 0.f, laP1 = 0.f;   // la_prev[jf]
    float laN0 = 0.f, laN1 = 0.f;   // la_new[kf]

    for (int ch = 0; ch < 8; ++ch) {
        if ((t >> 3) == ch) {       // stage this chunk's elp rows
            int tt = t & 7;
            float4* dst0 = reinterpret_cast<float4*>(&sElp[b0l][tt][0]);
            dst0[0] = make_float4(e0[0], e0[1], e0[2], e0[3]);
            dst0[1] = make_float4(e0[4], e0[5], e0[6], e0[7]);
            float4* dst1 = reinterpret_cast<float4*>(&sElp[b1l][tt][0]);
            dst1[0] = make_float4(e1[0], e1[1], e1[2], e1[3]);
            dst1[1] = make_float4(e1[4], e1[5], e1[6], e1[7]);
        }
        __syncthreads();
#pragma unroll
        for (int ts = 0; ts < 8; ++ts) {
            if (ch == 0 && ts == 0) {
                laP0 = liJ + sElp[b0l][0][jf];
                laP1 = liJ + sElp[b1l][0][jf];
                laN0 = liK + sElp[b0l][0][kf];
                laN1 = liK + sElp[b1l][0][kf];
            } else {
                float t0 = laP0 + lt, t1 = laP1 + lt;
                float m0 = t0, m1 = t1;
                m0 = fmaxf(m0, __shfl_xor(m0, 1)); m1 = fmaxf(m1, __shfl_xor(m1, 1));
                m0 = fmaxf(m0, __shfl_xor(m0, 2)); m1 = fmaxf(m1, __shfl_xor(m1, 2));
                m0 = fmaxf(m0, __shfl_xor(m0, 4)); m1 = fmaxf(m1, __shfl_xor(m1, 4));
                float s0 = expf(t0 - m0), s1 = expf(t1 - m1);
                s0 += __shfl_xor(s0, 1); s1 += __shfl_xor(s1, 1);
                s0 += __shfl_xor(s0, 2); s1 += __shfl_xor(s1, 2);
                s0 += __shfl_xor(s0, 4); s1 += __shfl_xor(s1, 4);
                laN0 = m0 + logf(s0) + sElp[b0l][ts][kf];
                laN1 = m1 + logf(s1) + sElp[b1l][ts][kf];
                laP0 = __shfl(laN0, jf << 3);   // redistribute la[j] for next step
                laP1 = __shfl(laN1, jf << 3);
            }
        }
        __syncthreads();
    }

    // argmax state (first-index on ties, like jnp.argmax)
    float bst0 = -INFINITY, bst1 = -INFINITY;
    int s00 = 0, s01 = 0;
#pragma unroll
    for (int k = 0; k < KK; ++k) {
        float v0 = __shfl(laN0, k * 8);
        float v1 = __shfl(laN1, k * 8);
        if (v0 > bst0) { bst0 = v0; s00 = k; }
        if (v1 > bst1) { bst1 = v1; s01 = k; }
    }

    // ---------------- Phase C: P-step autoregressive rollout ----------------
    float* bf0 = &sBuf[b0l][0];
    float* bf1 = &sBuf[b1l][0];
    for (int p = 0; p < PP; ++p) {
        int sa = (int)sChain[s00][p];
        int sb = (int)sChain[s01][p];
        float4 x0 = bv0[64 + p + t];       // window [p, p+63] of rolling buffer
        float4 x1 = bv1[64 + p + t];
        float pr0[CCH], pr1[CCH];
#pragma unroll
        for (int c = 0; c < CCH; ++c) {
            float4 w0 = Wv[(sa * CCH + c) * LL + t];   // global, L1-hot, coalesced
            float4 w1 = Wv[(sb * CCH + c) * LL + t];
            pr0[c] = fmaf(x0.w, w0.w, fmaf(x0.z, w0.z, fmaf(x0.y, w0.y, x0.x * w0.x)));
            pr1[c] = fmaf(x1.w, w1.w, fmaf(x1.z, w1.z, fmaf(x1.y, w1.y, x1.x * w1.x)));
        }
#pragma unroll
        for (int c = 0; c < CCH; ++c) {
#pragma unroll
            for (int d = 1; d < 64; d <<= 1) {
                pr0[c] += __shfl_xor(pr0[c], d);
                pr1[c] += __shfl_xor(pr1[c], d);
            }
            pr0[c] += sMean[sa][c];
            pr1[c] += sMean[sb][c];
        }
        int cw = lane & 3;
        float v0 = (cw == 0) ? pr0[0] : (cw == 1) ? pr0[1] : (cw == 2) ? pr0[2] : pr0[3];
        float v1 = (cw == 0) ? pr1[0] : (cw == 1) ? pr1[1] : (cw == 2) ? pr1[2] : pr1[3];
        if (lane < 4) {
            bf0[(128 + p) * 4 + cw] = v0;                       // append pred to buffer
            out[(bBase + b0l) * (PP * CCH) + p * CCH + cw] = v0;
        } else if (lane < 8) {
            bf1[(128 + p) * 4 + cw] = v1;
            out[(bBase + b1l) * (PP * CCH) + p * CCH + cw] = v1;
        }
        __syncthreads();
    }
}

extern "C" void kernel_launch(void* const* d_in, const int* in_sizes, int n_in,
                              void* d_out, int out_size, void* d_ws, size_t ws_size,
                              hipStream_t stream) {
    (void)in_sizes; (void)n_in; (void)d_ws; (void)ws_size; (void)out_size;
    const float* em  = (const float*)d_in[0];
    const float* trm = (const float*)d_in[1];
    const float* ini = (const float*)d_in[2];
    const float* mns = (const float*)d_in[3];
    const float* cvc = (const float*)d_in[4];
    const float* Wg  = (const float*)d_in[5];
    float* out = (float*)d_out;
    dim3 grid(BB / BPB), block(NTHR);
    hipLaunchKernelGGL(lahmm_fused, grid, block, 0, stream,
                       em, trm, ini, mns, cvc, Wg, out);
}